// Round 8
// baseline (5198.397 us; speedup 1.0000x reference)
//
#include <hip/hip_runtime.h>

// ---------------- problem constants ----------------
constexpr int Bn = 128, Tn = 256, An = 16, Ln = 256, Sn = 32, Dn = 512, Hn = 512;
constexpr int STLD = 544;         // st row = [h(512), z(32)]
constexpr int GK   = 576;         // gates K padded: [h 512, z 32, a 16, pad 16]
constexpr int GRID = 64;          // persistent WGs (<= 256 CUs -> always co-resident)
constexpr int GWP  = 584;         // LDS gw row stride (conflict-free padding)

typedef __bf16 bf16x8 __attribute__((ext_vector_type(8)));
typedef float  f32x4  __attribute__((ext_vector_type(4)));
typedef unsigned short u16;
typedef unsigned long long u64;

__device__ __forceinline__ f32x4 mfma16(bf16x8 a, bf16x8 b, f32x4 c) {
  return __builtin_amdgcn_mfma_f32_16x16x32_bf16(a, b, c, 0, 0, 0);
}
__device__ __forceinline__ bf16x8 ld8(const u16* p) {
  return *reinterpret_cast<const bf16x8*>(p);
}
// Agent-scope relaxed (sc0+sc1) bypass accesses: serve at the MALL coherence
// point. Used for cross-WG data (st_all h, q1, z outputs) and barrier flags.
__device__ __forceinline__ bf16x8 ld8c(const u16* p) {
  union { u64 q[2]; bf16x8 v; } u;
  u.q[0] = __hip_atomic_load((const u64*)p,       __ATOMIC_RELAXED, __HIP_MEMORY_SCOPE_AGENT);
  u.q[1] = __hip_atomic_load((const u64*)(p + 4), __ATOMIC_RELAXED, __HIP_MEMORY_SCOPE_AGENT);
  return u.v;
}
__device__ __forceinline__ void st2c(u16* p, u16 v) {
  __hip_atomic_store(p, v, __ATOMIC_RELAXED, __HIP_MEMORY_SCOPE_AGENT);
}
__device__ __forceinline__ void st4c(float* p, float v) {
  __hip_atomic_store(p, v, __ATOMIC_RELAXED, __HIP_MEMORY_SCOPE_AGENT);
}
__device__ __forceinline__ f32x4 fz4() { f32x4 v = {0.f, 0.f, 0.f, 0.f}; return v; }
__device__ __forceinline__ u16 f2b(float f) {           // RNE f32 -> bf16 bits
  unsigned u = __float_as_uint(f);
  unsigned r = (u + 0x7fffu + ((u >> 16) & 1u)) >> 16;
  return (u16)r;
}
__device__ __forceinline__ float b2f(u16 x) { return __uint_as_float(((unsigned)x) << 16); }
__device__ __forceinline__ float sigm(float x) { return 1.f / (1.f + expf(-x)); }

// ---------------- weight / input conversion ----------------
__global__ void k_conv(const float* __restrict__ s, u16* __restrict__ d, int n) {
  int i = blockIdx.x * 256 + threadIdx.x;
  if (i < n) d[i] = f2b(s[i]);
}
// src [K][N] row-major f32  ->  dst[(n+nOff)*ld + kOff + k] bf16  (transposed)
__global__ void k_tconv(const float* __restrict__ s, u16* __restrict__ d,
                        int K, int N, int ld, int nOff, int kOff) {
  int i = blockIdx.x * 256 + threadIdx.x;
  if (i >= K * N) return;
  int k = i / N, n = i - k * N;
  d[(n + nOff) * ld + kOff + k] = f2b(s[i]);
}
__global__ void k_padWg(u16* __restrict__ d) {  // zero Wgt[:, 560:576]
  int i = blockIdx.x * 256 + threadIdx.x;
  if (i >= 1536 * 16) return;
  int n = i >> 4, j = i & 15;
  d[n * GK + 560 + j] = 0;
}
__global__ void k_zeroN(unsigned* p, int n) {
  int i = blockIdx.x * 256 + threadIdx.x;
  if (i < n) p[i] = 0u;
}

// ------- split barrier: thin drain + deferred-store window + parallel poll ---
// Two independent 32-WG domains (row-halves never exchange data). post_wg:
// per-wave vmcnt drain (exchange stores only; output stores are issued AFTER
// the flag and retire during the poll), syncthreads, post per-WG flag.
// wait_all32: 32 lanes poll 32 flags in one parallel relaxed agent load.
// No acquire/release fences anywhere (all cross-WG data is sc0/sc1 bypass).
__device__ __forceinline__ void post_wg(unsigned* gflags, int idx, unsigned val) {
  asm volatile("s_waitcnt vmcnt(0) lgkmcnt(0)" ::: "memory");
  __syncthreads();
  if (threadIdx.x == 0)
    __hip_atomic_store(gflags + idx * 32, val, __ATOMIC_RELAXED, __HIP_MEMORY_SCOPE_AGENT);
}
__device__ __forceinline__ void wait_all32(unsigned* gflags, unsigned tgt) {
  if (threadIdx.x < 64) {
    const int l = threadIdx.x & 31;
    for (;;) {
      unsigned v = __hip_atomic_load(gflags + l * 32, __ATOMIC_RELAXED, __HIP_MEMORY_SCOPE_AGENT);
      if (__all((int)(v >= tgt))) break;
      __builtin_amdgcn_s_sleep(1);
    }
  }
  __syncthreads();
}

// ---------------- persistent sequential kernel ----------------
struct SeqArgs {
  const u16* h0b;      // [128][512] bf16
  const u16* z0b;      // [128][32] bf16
  const float* h0;     // [128][512] f32
  const u16* actb;     // [B][T][16]
  const u16* obsb;     // [B][T][256]
  const float* eps;    // [B][T][32]
  const u16* Wgt;      // [1536][576]
  const float* bih; const float* bhh;
  const u16* qW1t;     // [512][768]
  const u16* qW2t;     // [64][512]
  const float* qb1; const float* qb2;
  u16* st_all;         // [B*T][544]
  u16* q1;             // [128][512]
  float* out_h; float* out_z; float* out_pomu; float* out_pols;
  unsigned* flags;     // [2 halves][32 wg][32 u32 pad]
};

__global__ __launch_bounds__(256, 1) void k_seq(SeqArgs A) {
  __shared__ u16 gw[48 * GWP];
  __shared__ u16 zl[4][16][40];   // per-WAVE z tile (16 rows x 32 cols, pad 40)
  const int tid = threadIdx.x, w = blockIdx.x;
  const int lane = tid & 63, wv = tid >> 6, quad = lane >> 4, r16 = lane & 15;
  const int wq = w & 31;                // index within half
  const int cslice = wq * 16;           // 16-col slice (GRU h-cols & L1 cols)
  const int mh = w >> 5;                // M-half (independent barrier domain)
  const int mrow0 = mh * 64 + wv * 16;  // this wave's 16 batch rows
  unsigned* gflags = A.flags + mh * 32 * 32;
  const bool desig = (wq == 0);         // z/out writer WG per half
  const bf16x8 z8 = {(__bf16)0.f,(__bf16)0.f,(__bf16)0.f,(__bf16)0.f,
                     (__bf16)0.f,(__bf16)0.f,(__bf16)0.f,(__bf16)0.f};

  // stage GRU weight slice into LDS: rows {r,u,n}x16cols, K=576 (pad to 584)
  for (int idx = tid; idx < 48 * 72; idx += 256) {
    int r = idx / 72, c = idx - r * 72;
    int g = r >> 4, rr = r & 15;
    const u16* src = A.Wgt + (g * 512 + cslice + rr) * GK + c * 8;
    *(uint4*)&gw[r * GWP + c * 8] = *(const uint4*)src;
  }
  // L1 weight frags -> registers (reused all 256 steps)
  bf16x8 lwreg[24];
#pragma unroll
  for (int kc = 0; kc < 24; ++kc)
    lwreg[kc] = ld8(A.qW1t + (cslice + r16) * 768 + kc * 32 + quad * 8);
  // loop-invariant biases -> registers
  const int ch = cslice + r16;
  const float br_  = A.bih[ch] + A.bhh[ch];
  const float bu_  = A.bih[Dn + ch] + A.bhh[Dn + ch];
  const float bni_ = A.bih[2 * Dn + ch];
  const float bnh_ = A.bhh[2 * Dn + ch];
  const float qb_  = A.qb1[ch];
  float bm_[2], bl_[2];
#pragma unroll
  for (int n2 = 0; n2 < 2; ++n2) {
    bm_[n2] = A.qb2[n2 * 16 + r16];
    bl_[n2] = A.qb2[n2 * 16 + r16 + Sn];
  }
  // carried h (f32) for this lane's 4 (row,col) cells
  float hcar[4];
#pragma unroll
  for (int i = 0; i < 4; ++i)
    hcar[i] = A.h0[(mrow0 + quad * 4 + i) * Dn + ch];
  // h A-fragments in registers: reloaded by B(t) from st_all(t), consumed by
  // the gate h-part of step t+1 (identical bf16 values -> no re-gather).
  bf16x8 a_h[16];
#pragma unroll
  for (int kc = 0; kc < 16; ++kc)
    a_h[kc] = ld8(A.h0b + (mrow0 + r16) * Dn + kc * 32 + quad * 8);
  // z0 -> wave-private LDS tile
  {
    bf16x8 zv0 = ld8(A.z0b + (mrow0 + r16) * Sn + quad * 8);
    *reinterpret_cast<bf16x8*>(&zl[wv][r16][quad * 8]) = zv0;
  }
  // prologue inputs for t = 0
  bf16x8 obs_pre[8];
#pragma unroll
  for (int kc = 0; kc < 8; ++kc)
    obs_pre[kc] = ld8(A.obsb + ((mrow0 + r16) * Tn + 0) * Ln + kc * 32 + quad * 8);
  bf16x8 act_pre = z8;
  if (quad < 2) act_pre = ld8(A.actb + ((mrow0 + r16) * Tn + 0) * An + quad * 8);
  float eps_pre[2][4];
#pragma unroll
  for (int n2 = 0; n2 < 2; ++n2)
#pragma unroll
    for (int i = 0; i < 4; ++i)
      eps_pre[n2][i] = A.eps[((long)(mrow0 + quad * 4 + i) * Tn + 0) * Sn + n2 * 16 + r16];
  __syncthreads();

  // ================= prologue: full gates for t = 0 =================
  f32x4 aR = fz4(), aU = fz4(), aNh = fz4(), aNi = fz4();
#pragma unroll
  for (int kc = 0; kc < 16; ++kc) {
    const int k = kc * 32 + quad * 8;
    aR  = mfma16(a_h[kc], ld8(&gw[r16 * GWP + k]), aR);
    aU  = mfma16(a_h[kc], ld8(&gw[(16 + r16) * GWP + k]), aU);
    aNh = mfma16(a_h[kc], ld8(&gw[(32 + r16) * GWP + k]), aNh);
  }
  {  // act columns
    const int k = 544 + quad * 8;
    aR  = mfma16(act_pre, ld8(&gw[r16 * GWP + k]), aR);
    aU  = mfma16(act_pre, ld8(&gw[(16 + r16) * GWP + k]), aU);
    aNi = mfma16(act_pre, ld8(&gw[(32 + r16) * GWP + k]), aNi);
  }
  {  // z columns (from zl)
    const int k = 512 + quad * 8;
    bf16x8 zf = ld8(&zl[wv][r16][quad * 8]);
    aR  = mfma16(zf, ld8(&gw[r16 * GWP + k]), aR);
    aU  = mfma16(zf, ld8(&gw[(16 + r16) * GWP + k]), aU);
    aNi = mfma16(zf, ld8(&gw[(32 + r16) * GWP + k]), aNi);
  }
  float hvf[4];
#pragma unroll
  for (int i = 0; i < 4; ++i) {
    const float r = sigm(aR[i] + br_);
    const float u = sigm(aU[i] + bu_);
    const float n = tanhf(aNi[i] + bni_ + r * (aNh[i] + bnh_));
    const float hv = (1.f - u) * n + u * hcar[i];
    hcar[i] = hv; hvf[i] = hv;
    st2c(&A.st_all[((long)(mrow0 + quad * 4 + i) * Tn + 0) * STLD + ch], f2b(hv));
  }
  post_wg(gflags, wq, 1u);
#pragma unroll
  for (int i = 0; i < 4; ++i)    // deferred out_h(0)
    A.out_h[((long)(mrow0 + quad * 4 + i) * Tn + 0) * Dn + ch] = hvf[i];
  // q obs-part for t = 0 (shadow of wait1)
  f32x4 q = fz4();
#pragma unroll
  for (int kc = 0; kc < 8; ++kc)
    q = mfma16(obs_pre[kc], lwreg[16 + kc], q);
  // prefetch t = 1 inputs
  {
    const int t1 = 1;
#pragma unroll
    for (int kc = 0; kc < 8; ++kc)
      obs_pre[kc] = ld8(A.obsb + ((mrow0 + r16) * Tn + t1) * Ln + kc * 32 + quad * 8);
    act_pre = z8;
    if (quad < 2) act_pre = ld8(A.actb + ((mrow0 + r16) * Tn + t1) * An + quad * 8);
  }

  for (int t = 0; t < Tn; ++t) {
    const unsigned f1 = 2 * (unsigned)t + 1, f2 = f1 + 1;
    wait_all32(gflags, f1);            // h(t) visible

    // ================= B(t): posterior L1 =================
#pragma unroll
    for (int kc = 0; kc < 16; ++kc)
      a_h[kc] = ld8(A.st_all + ((long)(mrow0 + r16) * Tn + t) * STLD + kc * 32 + quad * 8);
#pragma unroll
    for (int kc = 0; kc < 16; ++kc)
      q = mfma16(a_h[kc], lwreg[kc], q);
#pragma unroll
    for (int i = 0; i < 4; ++i)
      st2c(&A.q1[(mrow0 + quad * 4 + i) * Hn + ch], f2b(fmaxf(q[i] + qb_, 0.f)));
    post_wg(gflags, wq, f2);

    // ======= gate h-part for step t+1 (shadows flag2 propagation) =======
    if (t < Tn - 1) {
      aR = fz4(); aU = fz4(); aNh = fz4();
#pragma unroll
      for (int kc = 0; kc < 16; ++kc) {
        const int k = kc * 32 + quad * 8;
        aR  = mfma16(a_h[kc], ld8(&gw[r16 * GWP + k]), aR);
        aU  = mfma16(a_h[kc], ld8(&gw[(16 + r16) * GWP + k]), aU);
        aNh = mfma16(a_h[kc], ld8(&gw[(32 + r16) * GWP + k]), aNh);
      }
    }
    wait_all32(gflags, f2);            // q1(t) visible

    // ===== C(t): posterior L2 + sample, LOCAL per wave (own 16 rows) =====
    // q1 bytes identical for every reader -> z bitwise consistent across the
    // redundant computations; WG 0 of each half writes the global outputs.
    {
      bf16x8 qa[16];
#pragma unroll
      for (int kc = 0; kc < 16; ++kc)  // full gather issued up front
        qa[kc] = ld8c(A.q1 + (mrow0 + r16) * Hn + kc * 32 + quad * 8);
      f32x4 cm0 = fz4(), cm1 = fz4(), cm2 = fz4(), cm3 = fz4();
#pragma unroll
      for (int kc = 0; kc < 16; ++kc) {
        const int k = kc * 32 + quad * 8;
        cm0 = mfma16(qa[kc], ld8(A.qW2t + (r16) * 512 + k), cm0);
        cm1 = mfma16(qa[kc], ld8(A.qW2t + (16 + r16) * 512 + k), cm1);
        cm2 = mfma16(qa[kc], ld8(A.qW2t + (32 + r16) * 512 + k), cm2);
        cm3 = mfma16(qa[kc], ld8(A.qW2t + (48 + r16) * 512 + k), cm3);
      }
#pragma unroll
      for (int n2 = 0; n2 < 2; ++n2) {
        const f32x4 cmu = n2 ? cm1 : cm0;
        const f32x4 cls = n2 ? cm3 : cm2;
        const int col = n2 * 16 + r16;
#pragma unroll
        for (int i = 0; i < 4; ++i) {
          const int b = mrow0 + quad * 4 + i;
          const float mu = cmu[i] + bm_[n2];
          const float ls = fminf(fmaxf(cls[i] + bl_[n2], -10.f), 2.f);
          const float z = mu + eps_pre[n2][i] * expf(ls);
          zl[wv][quad * 4 + i][col] = f2b(z);
          if (desig) {
            const long o = ((long)b * Tn + t) * Sn + col;
            st4c(&A.out_z[o], z); st4c(&A.out_pomu[o], mu); st4c(&A.out_pols[o], ls);
            st2c(&A.st_all[((long)b * Tn + t) * STLD + Dn + col], f2b(z));
          }
        }
      }
    }
    if (t == Tn - 1) break;            // C(255) done: all outputs written

    // ================= gate tail for t+1: act + z columns =================
    aNi = fz4();
    {
      const int k = 544 + quad * 8;
      aR  = mfma16(act_pre, ld8(&gw[r16 * GWP + k]), aR);
      aU  = mfma16(act_pre, ld8(&gw[(16 + r16) * GWP + k]), aU);
      aNi = mfma16(act_pre, ld8(&gw[(32 + r16) * GWP + k]), aNi);
    }
    {
      const int k = 512 + quad * 8;
      bf16x8 zf = ld8(&zl[wv][r16][quad * 8]);
      aR  = mfma16(zf, ld8(&gw[r16 * GWP + k]), aR);
      aU  = mfma16(zf, ld8(&gw[(16 + r16) * GWP + k]), aU);
      aNi = mfma16(zf, ld8(&gw[(32 + r16) * GWP + k]), aNi);
    }
#pragma unroll
    for (int i = 0; i < 4; ++i) {
      const float r = sigm(aR[i] + br_);
      const float u = sigm(aU[i] + bu_);
      const float n = tanhf(aNi[i] + bni_ + r * (aNh[i] + bnh_));
      const float hv = (1.f - u) * n + u * hcar[i];
      hcar[i] = hv; hvf[i] = hv;
      st2c(&A.st_all[((long)(mrow0 + quad * 4 + i) * Tn + (t + 1)) * STLD + ch], f2b(hv));
    }
    post_wg(gflags, wq, f2 + 1);       // flag1(t+1)
#pragma unroll
    for (int i = 0; i < 4; ++i)        // deferred out_h(t+1)
      A.out_h[((long)(mrow0 + quad * 4 + i) * Tn + (t + 1)) * Dn + ch] = hvf[i];
    // q obs-part for t+1 (shadow of wait1) + prefetch t+2 inputs
    q = fz4();
#pragma unroll
    for (int kc = 0; kc < 8; ++kc)
      q = mfma16(obs_pre[kc], lwreg[16 + kc], q);
    {
      const int t2 = (t + 2 < Tn) ? t + 2 : Tn - 1;
#pragma unroll
      for (int kc = 0; kc < 8; ++kc)
        obs_pre[kc] = ld8(A.obsb + ((mrow0 + r16) * Tn + t2) * Ln + kc * 32 + quad * 8);
      act_pre = z8;
      if (quad < 2) act_pre = ld8(A.actb + ((mrow0 + r16) * Tn + t2) * An + quad * 8);
#pragma unroll
      for (int n2 = 0; n2 < 2; ++n2)
#pragma unroll
        for (int i = 0; i < 4; ++i)
          eps_pre[n2][i] =
            A.eps[((long)(mrow0 + quad * 4 + i) * Tn + (t + 1)) * Sn + n2 * 16 + r16];
    }
  }
}

// ---------------- batched prior MLP over all B*T rows ----------------
__global__ __launch_bounds__(256) void k_prior(
    const u16* __restrict__ st_all,
    const u16* __restrict__ pW1t, const float* __restrict__ pb1,
    const u16* __restrict__ pW2t, const float* __restrict__ pb2,
    float* __restrict__ out_pmu, float* __restrict__ out_pls)
{
  __shared__ u16 hid[64 * 512];
  const int tid = threadIdx.x, lane = tid & 63, wv = tid >> 6;
  const int quad = lane >> 4, r16 = lane & 15;
  const int m0 = blockIdx.x * 64;
  f32x4 acc[4][8];
#pragma unroll
  for (int a = 0; a < 4; ++a)
#pragma unroll
    for (int c = 0; c < 8; ++c) acc[a][c] = fz4();
  for (int kc = 0; kc < 16; ++kc) {
    const int k = kc * 32 + quad * 8;
    bf16x8 av[4];
#pragma unroll
    for (int rb = 0; rb < 4; ++rb)
      av[rb] = ld8(st_all + (long)(m0 + rb * 16 + r16) * STLD + k);
#pragma unroll
    for (int cb = 0; cb < 8; ++cb) {
      bf16x8 bb = ld8(pW1t + (wv * 128 + cb * 16 + r16) * Dn + k);
#pragma unroll
      for (int rb = 0; rb < 4; ++rb) acc[rb][cb] = mfma16(av[rb], bb, acc[rb][cb]);
    }
  }
#pragma unroll
  for (int rb = 0; rb < 4; ++rb)
#pragma unroll
    for (int cb = 0; cb < 8; ++cb) {
      const int col = wv * 128 + cb * 16 + r16;
      const float pb = pb1[col];
#pragma unroll
      for (int i = 0; i < 4; ++i) {
        const int row = rb * 16 + quad * 4 + i;
        hid[row * 512 + ((col + row * 8) & 511)] = f2b(fmaxf(acc[rb][cb][i] + pb, 0.f));
      }
    }
  __syncthreads();
  f32x4 acc2[4];
#pragma unroll
  for (int rb = 0; rb < 4; ++rb) acc2[rb] = fz4();
  for (int kc = 0; kc < 16; ++kc) {
    const int k = kc * 32 + quad * 8;
    bf16x8 bb = ld8(pW2t + (wv * 16 + r16) * Dn + k);
#pragma unroll
    for (int rb = 0; rb < 4; ++rb) {
      const int row = rb * 16 + r16;
      bf16x8 aa = ld8(&hid[row * 512 + ((k + row * 8) & 511)]);
      acc2[rb] = mfma16(aa, bb, acc2[rb]);
    }
  }
  const int col = wv * 16 + r16;
#pragma unroll
  for (int rb = 0; rb < 4; ++rb)
#pragma unroll
    for (int i = 0; i < 4; ++i) {
      const int r = m0 + rb * 16 + quad * 4 + i;
      float v = acc2[rb][i] + pb2[col];
      if (col < Sn) out_pmu[r * Sn + col] = v;
      else out_pls[r * Sn + col - Sn] = fminf(fmaxf(v, -10.f), 2.f);
    }
}

// ---------------- batched obs head ----------------
__global__ __launch_bounds__(256) void k_obs(
    const u16* __restrict__ st_all, const u16* __restrict__ hW1t,
    const float* __restrict__ ob1, const u16* __restrict__ oW2t,
    const float* __restrict__ ob2, float* __restrict__ out_obs)
{
  __shared__ u16 hid[64 * 512];
  const int tid = threadIdx.x, lane = tid & 63, wv = tid >> 6;
  const int quad = lane >> 4, r16 = lane & 15;
  const int m0 = blockIdx.x * 64;
  f32x4 acc[4][8];
#pragma unroll
  for (int a = 0; a < 4; ++a)
#pragma unroll
    for (int c = 0; c < 8; ++c) acc[a][c] = fz4();
  for (int kc = 0; kc < 17; ++kc) {
    const int k = kc * 32 + quad * 8;
    bf16x8 av[4];
#pragma unroll
    for (int rb = 0; rb < 4; ++rb)
      av[rb] = ld8(st_all + (long)(m0 + rb * 16 + r16) * STLD + k);
#pragma unroll
    for (int cb = 0; cb < 8; ++cb) {
      bf16x8 bb = ld8(hW1t + (wv * 128 + cb * 16 + r16) * STLD + k);
#pragma unroll
      for (int rb = 0; rb < 4; ++rb) acc[rb][cb] = mfma16(av[rb], bb, acc[rb][cb]);
    }
  }
#pragma unroll
  for (int rb = 0; rb < 4; ++rb)
#pragma unroll
    for (int cb = 0; cb < 8; ++cb) {
      const int col = wv * 128 + cb * 16 + r16;
      const float ob = ob1[col];
#pragma unroll
      for (int i = 0; i < 4; ++i) {
        const int row = rb * 16 + quad * 4 + i;
        hid[row * 512 + ((col + row * 8) & 511)] = f2b(fmaxf(acc[rb][cb][i] + ob, 0.f));
      }
    }
  __syncthreads();
  f32x4 acc2[4][4];
#pragma unroll
  for (int a = 0; a < 4; ++a)
#pragma unroll
    for (int c = 0; c < 4; ++c) acc2[a][c] = fz4();
  for (int kc = 0; kc < 16; ++kc) {
    const int k = kc * 32 + quad * 8;
    bf16x8 aa[4];
#pragma unroll
    for (int rb = 0; rb < 4; ++rb) {
      const int row = rb * 16 + r16;
      aa[rb] = ld8(&hid[row * 512 + ((k + row * 8) & 511)]);
    }
#pragma unroll
    for (int cb = 0; cb < 4; ++cb) {
      bf16x8 bb = ld8(oW2t + (wv * 64 + cb * 16 + r16) * Dn + k);
#pragma unroll
      for (int rb = 0; rb < 4; ++rb) acc2[rb][cb] = mfma16(aa[rb], bb, acc2[rb][cb]);
    }
  }
#pragma unroll
  for (int rb = 0; rb < 4; ++rb)
#pragma unroll
    for (int cb = 0; cb < 4; ++cb) {
      const int col = wv * 64 + cb * 16 + r16;
      const float ob = ob2[col];
#pragma unroll
      for (int i = 0; i < 4; ++i) {
        const int r = m0 + rb * 16 + quad * 4 + i;
        out_obs[r * Ln + col] = acc2[rb][cb][i] + ob;
      }
    }
}

// ---------------- batched reward + done heads ----------------
__global__ __launch_bounds__(256) void k_rewdone(
    const u16* __restrict__ st_all, const u16* __restrict__ hW1t,
    const float* __restrict__ rb1, const float* __restrict__ rW2, const float* __restrict__ rb2,
    const float* __restrict__ db1, const float* __restrict__ dW2, const float* __restrict__ db2,
    float* __restrict__ out_rew, float* __restrict__ out_done)
{
  __shared__ u16 hid[64 * 512];
  const int tid = threadIdx.x, lane = tid & 63, wv = tid >> 6;
  const int quad = lane >> 4, r16 = lane & 15;
  const int m0 = blockIdx.x * 64;

  for (int head = 0; head < 2; ++head) {
    const float* b1 = head ? db1 : rb1;
    const float* w2 = head ? dW2 : rW2;
    float* outp = head ? out_done : out_rew;
    const int nb = 512 + head * 512;

    f32x4 acc[4][8];
#pragma unroll
    for (int a = 0; a < 4; ++a)
#pragma unroll
      for (int c = 0; c < 8; ++c) acc[a][c] = fz4();
    for (int kc = 0; kc < 17; ++kc) {
      const int k = kc * 32 + quad * 8;
      bf16x8 av[4];
#pragma unroll
      for (int rb = 0; rb < 4; ++rb)
        av[rb] = ld8(st_all + (long)(m0 + rb * 16 + r16) * STLD + k);
#pragma unroll
      for (int cb = 0; cb < 8; ++cb) {
        bf16x8 bb = ld8(hW1t + (nb + wv * 128 + cb * 16 + r16) * STLD + k);
#pragma unroll
        for (int rb = 0; rb < 4; ++rb) acc[rb][cb] = mfma16(av[rb], bb, acc[rb][cb]);
      }
    }
#pragma unroll
    for (int rb = 0; rb < 4; ++rb)
#pragma unroll
      for (int cb = 0; cb < 8; ++cb) {
        const int col = wv * 128 + cb * 16 + r16;
        const float bv = b1[col];
#pragma unroll
        for (int i = 0; i < 4; ++i) {
          const int row = rb * 16 + quad * 4 + i;
          hid[row * 512 + ((col + row * 8) & 511)] = f2b(fmaxf(acc[rb][cb][i] + bv, 0.f));
        }
      }
    __syncthreads();
    const int row = tid >> 2, part = tid & 3;
    float s = 0.f;
    for (int c = part * 128; c < part * 128 + 128; ++c)
      s += b2f(hid[row * 512 + ((c + row * 8) & 511)]) * w2[c];
    s += __shfl_xor(s, 1);
    s += __shfl_xor(s, 2);
    if (part == 0) outp[m0 + row] = s + (head ? db2[0] : rb2[0]);
    __syncthreads();
  }
}

// ---------------- host ----------------
extern "C" void kernel_launch(void* const* d_in, const int* in_sizes, int n_in,
                              void* d_out, int out_size, void* d_ws, size_t ws_size,
                              hipStream_t stream) {
  const float* actions = (const float*)d_in[0];
  const float* obs     = (const float*)d_in[1];
  const float* eps     = (const float*)d_in[2];
  const float* h0      = (const float*)d_in[3];
  const float* z0      = (const float*)d_in[4];
  const float* Wih     = (const float*)d_in[5];
  const float* Whh     = (const float*)d_in[6];
  const float* bih     = (const float*)d_in[7];
  const float* bhh     = (const float*)d_in[8];
  const float* pW1     = (const float*)d_in[9];
  const float* pb1     = (const float*)d_in[10];
  const float* pW2     = (const float*)d_in[11];
  const float* pb2     = (const float*)d_in[12];
  const float* qW1     = (const float*)d_in[13];
  const float* qb1     = (const float*)d_in[14];
  const float* qW2     = (const float*)d_in[15];
  const float* qb2     = (const float*)d_in[16];
  const float* oW1     = (const float*)d_in[17];
  const float* ob1     = (const float*)d_in[18];
  const float* oW2     = (const float*)d_in[19];
  const float* ob2     = (const float*)d_in[20];
  const float* rW1     = (const float*)d_in[21];
  const float* rb1     = (const float*)d_in[22];
  const float* rW2     = (const float*)d_in[23];
  const float* rb2     = (const float*)d_in[24];
  const float* dW1     = (const float*)d_in[25];
  const float* db1     = (const float*)d_in[26];
  const float* dW2     = (const float*)d_in[27];
  const float* db2     = (const float*)d_in[28];

  float* out = (float*)d_out;
  float* out_h    = out;                  // [B,T,512]
  float* out_z    = out + 16777216;       // [B,T,32]
  float* out_obs  = out + 17825792;       // [B,T,256]
  float* out_rew  = out + 26214400;       // [B,T]
  float* out_done = out + 26247168;       // [B,T]
  float* out_prmu = out + 26279936;       // [B,T,32]
  float* out_prls = out + 27328512;       // [B,T,32]
  float* out_pomu = out + 28377088;       // [B,T,32]
  float* out_pols = out + 29425664;       // [B,T,32]

  char* w = (char*)d_ws;
  u16* WGT  = (u16*)(w + 0);          // [1536][576]
  u16* QW1T = (u16*)(w + 1769472);    // [512][768]
  u16* QW2T = (u16*)(w + 2555904);    // [64][512]
  u16* PW1T = (u16*)(w + 2621440);    // [512][512]
  u16* PW2T = (u16*)(w + 3145728);    // [64][512]
  u16* HW1T = (u16*)(w + 3211264);    // [1536][544] (obs|rew|done)
  u16* OW2T = (u16*)(w + 4882432);    // [256][512]
  u16* H0B  = (u16*)(w + 5144576);    // [128][512]
  u16* ACTB = (u16*)(w + 5275648);    // [B][T][16]
  u16* OBSB = (u16*)(w + 6324224);    // [B][T][256]
  u16* STALL= (u16*)(w + 23101440);   // [B*T][544]
  u16* Q1   = (u16*)(w + 58753024);   // [128][512]
  u16* Z0B  = (u16*)(w + 58884096);   // [128][32]
  unsigned* FLAGS = (unsigned*)(w + 58892288);  // [2][32][32] u32 = 8KB

  auto nb = [](int n) { return dim3((unsigned)((n + 255) / 256)); };

  k_zeroN<<<nb(2048), 256, 0, stream>>>(FLAGS, 2048);
  k_conv<<<nb(128 * 512), 256, 0, stream>>>(h0, H0B, 128 * 512);
  k_conv<<<nb(128 * 32), 256, 0, stream>>>(z0, Z0B, 128 * 32);
  k_conv<<<nb(128 * 256 * 16), 256, 0, stream>>>(actions, ACTB, 128 * 256 * 16);
  k_conv<<<nb(128 * 256 * 256), 256, 0, stream>>>(obs, OBSB, 128 * 256 * 256);
  k_tconv<<<nb(512 * 1536), 256, 0, stream>>>(Whh, WGT, 512, 1536, GK, 0, 0);
  k_tconv<<<nb(48 * 1536), 256, 0, stream>>>(Wih, WGT, 48, 1536, GK, 0, 512);
  k_padWg<<<nb(1536 * 16), 256, 0, stream>>>(WGT);
  k_tconv<<<nb(768 * 512), 256, 0, stream>>>(qW1, QW1T, 768, 512, 768, 0, 0);
  k_tconv<<<nb(512 * 64), 256, 0, stream>>>(qW2, QW2T, 512, 64, 512, 0, 0);
  k_tconv<<<nb(512 * 512), 256, 0, stream>>>(pW1, PW1T, 512, 512, 512, 0, 0);
  k_tconv<<<nb(512 * 64), 256, 0, stream>>>(pW2, PW2T, 512, 64, 512, 0, 0);
  k_tconv<<<nb(544 * 512), 256, 0, stream>>>(oW1, HW1T, 544, 512, STLD, 0, 0);
  k_tconv<<<nb(544 * 512), 256, 0, stream>>>(rW1, HW1T, 544, 512, STLD, 512, 0);
  k_tconv<<<nb(544 * 512), 256, 0, stream>>>(dW1, HW1T, 544, 512, STLD, 1024, 0);
  k_tconv<<<nb(512 * 256), 256, 0, stream>>>(oW2, OW2T, 512, 256, 512, 0, 0);

  SeqArgs sa;
  sa.h0b = H0B; sa.z0b = Z0B; sa.h0 = h0;
  sa.actb = ACTB; sa.obsb = OBSB; sa.eps = eps;
  sa.Wgt = WGT; sa.bih = bih; sa.bhh = bhh;
  sa.qW1t = QW1T; sa.qW2t = QW2T; sa.qb1 = qb1; sa.qb2 = qb2;
  sa.st_all = STALL; sa.q1 = Q1;
  sa.out_h = out_h; sa.out_z = out_z; sa.out_pomu = out_pomu; sa.out_pols = out_pols;
  sa.flags = FLAGS;
  k_seq<<<dim3(GRID), dim3(256), 0, stream>>>(sa);

  k_prior<<<512, 256, 0, stream>>>(STALL, PW1T, pb1, PW2T, pb2, out_prmu, out_prls);
  k_obs<<<512, 256, 0, stream>>>(STALL, HW1T, ob1, OW2T, ob2, out_obs);
  k_rewdone<<<512, 256, 0, stream>>>(STALL, HW1T, rb1, rW2, rb2, db1, dW2, db2,
                                     out_rew, out_done);
}